// Round 4
// baseline (1783.763 us; speedup 1.0000x reference)
//
#include <hip/hip_runtime.h>

#define N_NODES 500000
#define N_EDGES 8000000
#define N_GRAPHS 8192
#define POOL_CH 128
#define BKT 256                 // nodes per bucket
#define NB 1954                 // ceil(N_NODES / BKT)
#define TILE_E 16384            // edges per block in bucketing passes (256 thr * 64)
#define NTB 489                 // ceil(N_EDGES / TILE_E)

// ---------------- utility ----------------
__global__ void k_fill(float* __restrict__ p, float v, int n) {
    int i = blockIdx.x * 256 + threadIdx.x;
    if (i < n) p[i] = v;
}
__global__ void k_filli(int* __restrict__ p, int v, int n) {
    int i = blockIdx.x * 256 + threadIdx.x;
    if (i < n) p[i] = v;
}

// ---- pass A: per-bucket edge counts (LDS histogram, one flush per block) ----
__global__ void k_bcount(const int* __restrict__ col, int* __restrict__ gcnt, int E) {
    __shared__ int lcnt[NB];
    int t = threadIdx.x;
    for (int i = t; i < NB; i += 256) lcnt[i] = 0;
    __syncthreads();
    int base = blockIdx.x * TILE_E;
#pragma unroll 4
    for (int k = 0; k < 64; k++) {
        int e = base + k * 256 + t;
        if (e < E) {
            unsigned c = (unsigned)col[e];
            if (c < N_NODES) atomicAdd(&lcnt[c >> 8], 1);
        }
    }
    __syncthreads();
    for (int i = t; i < NB; i += 256)
        if (lcnt[i]) atomicAdd(&gcnt[i], lcnt[i]);
}

// ---- exclusive scan of bucket counts (single block) ----
__global__ void k_bscan(const int* __restrict__ gcnt, int* __restrict__ goff,
                        int* __restrict__ gcursor) {
    __shared__ int sd[256];
    int t = threadIdx.x;
    int v[8]; int s = 0;
    int base = t * 8;
#pragma unroll
    for (int k = 0; k < 8; k++) { int i = base + k; v[k] = (i < NB) ? gcnt[i] : 0; s += v[k]; }
    sd[t] = s; __syncthreads();
    for (int d = 1; d < 256; d <<= 1) {
        int tv = (t >= d) ? sd[t - d] : 0;
        __syncthreads(); sd[t] += tv; __syncthreads();
    }
    int run = sd[t] - s;  // exclusive prefix of this thread's chunk
#pragma unroll
    for (int k = 0; k < 8; k++) {
        int i = base + k;
        if (i < NB) { goff[i] = run; gcursor[i] = run; run += v[k]; }
    }
    if (t == 255) goff[NB] = run;
}

// ---- pass B: scatter packed (r<<8 | c_local) into bucket-grouped array ----
__global__ void k_bscatter(const int* __restrict__ row, const int* __restrict__ col,
                           int* __restrict__ gcursor, unsigned* __restrict__ packed, int E) {
    __shared__ int lcnt[NB];
    __shared__ int lbase[NB];
    int t = threadIdx.x;
    for (int i = t; i < NB; i += 256) lcnt[i] = 0;
    __syncthreads();
    int base = blockIdx.x * TILE_E;
#pragma unroll 4
    for (int k = 0; k < 64; k++) {
        int e = base + k * 256 + t;
        if (e < E) {
            unsigned c = (unsigned)col[e];
            if (c < N_NODES) atomicAdd(&lcnt[c >> 8], 1);
        }
    }
    __syncthreads();
    for (int i = t; i < NB; i += 256) {
        int c = lcnt[i];
        lbase[i] = c ? atomicAdd(&gcursor[i], c) : 0;
        lcnt[i] = 0;
    }
    __syncthreads();
    for (int k = 0; k < 64; k++) {
        int e = base + k * 256 + t;
        if (e < E) {
            unsigned c = (unsigned)col[e];
            unsigned r = (unsigned)row[e];
            if (c < N_NODES && r < N_NODES) {
                unsigned b = c >> 8;
                int pos = lbase[b] + atomicAdd(&lcnt[b], 1);
                packed[pos] = (r << 8) | (c & 255u);
            }
        }
    }
}

// ---- degree from bucketed list (LDS counters, coalesced dinv write) ----
__global__ void k_deg(const unsigned* __restrict__ packed, const int* __restrict__ goff,
                      float* __restrict__ dinv, int N) {
    __shared__ int cnt[BKT];
    int t = threadIdx.x;
    int b = blockIdx.x;
    cnt[t] = 0;
    __syncthreads();
    int s = goff[b], e = goff[b + 1];
    for (int i = s + t; i < e; i += 256)
        atomicAdd(&cnt[packed[i] & 255u], 1);
    __syncthreads();
    int v = b * BKT + t;
    if (v < N) dinv[v] = rsqrtf(1.0f + (float)cnt[t]);
}

// ---- layer-1 node transform: hs = (x @ W1) * dinv ----
__global__ void k_l1(const float* __restrict__ x, const float* __restrict__ W1,
                     const float* __restrict__ dinv, float* __restrict__ hs, int n) {
    int v = blockIdx.x * 256 + threadIdx.x;
    if (v >= n) return;
    float xi[9];
#pragma unroll
    for (int k = 0; k < 9; k++) xi[k] = x[v * 9 + k];
    float di = dinv[v];
#pragma unroll
    for (int j = 0; j < 16; j++) {
        float acc = 0.f;
#pragma unroll
        for (int k = 0; k < 9; k++) acc += xi[k] * W1[k * 16 + j];
        hs[v * 16 + j] = acc * di;
    }
}

// ---- bucketed aggregation: LDS accumulator per 256 target nodes ----
// agg[v] = hs[v] (self-loop) + sum over in-edges hs[r]; 16 lanes/edge,
// 4-way unrolled gathers for memory-level parallelism.
__global__ void k_agg(const unsigned* __restrict__ packed, const int* __restrict__ goff,
                      const float* __restrict__ hs, float* __restrict__ agg, int N) {
    __shared__ float acc[BKT * 16];
    int t = threadIdx.x;
    int b = blockIdx.x;
    int vbase = b * BKT;
    int nloc = N - vbase; if (nloc > BKT) nloc = BKT;
    int lim = nloc * 16;
#pragma unroll
    for (int k = 0; k < 16; k++) {
        int idx = k * 256 + t;
        if (idx < lim) acc[idx] = hs[vbase * 16 + idx];
    }
    __syncthreads();
    int s = goff[b], e = goff[b + 1];
    int j = t & 15;
    int g = t >> 4;  // 16 groups of 16 lanes
    int i = s + g;
    for (; i + 48 < e; i += 64) {
        unsigned w0 = packed[i];
        unsigned w1 = packed[i + 16];
        unsigned w2 = packed[i + 32];
        unsigned w3 = packed[i + 48];
        float v0 = hs[(w0 >> 8) * 16 + j];
        float v1 = hs[(w1 >> 8) * 16 + j];
        float v2 = hs[(w2 >> 8) * 16 + j];
        float v3 = hs[(w3 >> 8) * 16 + j];
        atomicAdd(&acc[(w0 & 255u) * 16 + j], v0);
        atomicAdd(&acc[(w1 & 255u) * 16 + j], v1);
        atomicAdd(&acc[(w2 & 255u) * 16 + j], v2);
        atomicAdd(&acc[(w3 & 255u) * 16 + j], v3);
    }
    for (; i < e; i += 16) {
        unsigned w = packed[i];
        float v = hs[(w >> 8) * 16 + j];
        atomicAdd(&acc[(w & 255u) * 16 + j], v);
    }
    __syncthreads();
#pragma unroll
    for (int k = 0; k < 16; k++) {
        int idx = k * 256 + t;
        if (idx < lim) agg[vbase * 16 + idx] = acc[idx];
    }
}

// ---- layer-2 node transform: h1 = relu(agg*dinv + b1); hs = (h1 @ W2)*dinv ----
__global__ void k_l2(const float* __restrict__ W2, const float* __restrict__ b1,
                     const float* __restrict__ dinv, const float* __restrict__ agg,
                     float* __restrict__ hs, int n) {
    int v = blockIdx.x * 256 + threadIdx.x;
    if (v >= n) return;
    float di = dinv[v];
    float h1[16];
#pragma unroll
    for (int j = 0; j < 16; j++) {
        float t = agg[v * 16 + j] * di + b1[j];
        h1[j] = t > 0.f ? t : 0.f;
    }
#pragma unroll
    for (int j = 0; j < 16; j++) {
        float acc = 0.f;
#pragma unroll
        for (int k = 0; k < 16; k++) acc += h1[k] * W2[k * 16 + j];
        hs[v * 16 + j] = acc * di;
    }
}

// ---- pool exploiting sorted batch ----
__global__ void k_pool2(const float* __restrict__ agg, const float* __restrict__ dinv,
                        const float* __restrict__ b2, const int* __restrict__ batch,
                        float* __restrict__ pooled, float* __restrict__ cnt, int n) {
    int tid = blockIdx.x * 256 + threadIdx.x;
    int chunk = tid >> 4;
    int j = tid & 15;
    int start = chunk * POOL_CH;
    if (start >= n) return;
    int end = start + POOL_CH;
    if (end > n) end = n;
    float bj = b2[j];
    int g_cur = batch[start];
    float acc = 0.f;
    float c_acc = 0.f;
    for (int v = start; v < end; v++) {
        int g = batch[v];
        if (g != g_cur) {
            atomicAdd(&pooled[g_cur * 16 + j], acc);
            if (j == 0) atomicAdd(&cnt[g_cur], c_acc);
            acc = 0.f; c_acc = 0.f; g_cur = g;
        }
        float t = agg[v * 16 + j] * dinv[v] + bj;
        acc += t > 0.f ? t : 0.f;
        c_acc += 1.f;
    }
    atomicAdd(&pooled[g_cur * 16 + j], acc);
    if (j == 0) atomicAdd(&cnt[g_cur], c_acc);
}

// ---- head MLP ----
__global__ void k_head(const float* __restrict__ pooled, const float* __restrict__ cnt,
                       const float* __restrict__ meta, const float* __restrict__ Wh1,
                       const float* __restrict__ bh1, const float* __restrict__ Wh2,
                       const float* __restrict__ bh2, float* __restrict__ out, int G) {
    int g = blockIdx.x * 256 + threadIdx.x;
    if (g >= G) return;
    float z[43];
    float c = cnt[g];
    c = c > 1.f ? c : 1.f;
#pragma unroll
    for (int j = 0; j < 16; j++) z[j] = pooled[g * 16 + j] / c;
#pragma unroll
    for (int j = 0; j < 27; j++) z[16 + j] = meta[g * 27 + j];
    float acc2 = bh2[0];
#pragma unroll
    for (int jj = 0; jj < 16; jj++) {
        float a = bh1[jj];
#pragma unroll
        for (int k = 0; k < 43; k++) a += z[k] * Wh1[k * 16 + jj];
        a = a > 0.f ? a : 0.f;
        acc2 += a * Wh2[jj];
    }
    out[g] = acc2;
}

extern "C" void kernel_launch(void* const* d_in, const int* in_sizes, int n_in,
                              void* d_out, int out_size, void* d_ws, size_t ws_size,
                              hipStream_t stream) {
    const float* x    = (const float*)d_in[0];
    const int*   ei   = (const int*)d_in[1];   // [2, E]: row then col
    const int*   batch= (const int*)d_in[2];
    const float* meta = (const float*)d_in[3];
    const float* W1   = (const float*)d_in[4];
    const float* b1   = (const float*)d_in[5];
    const float* W2   = (const float*)d_in[6];
    const float* b2   = (const float*)d_in[7];
    const float* Wh1  = (const float*)d_in[8];
    const float* bh1  = (const float*)d_in[9];
    const float* Wh2  = (const float*)d_in[10];
    const float* bh2  = (const float*)d_in[11];
    float* out = (float*)d_out;

    const int N = N_NODES, E = N_EDGES, G = N_GRAPHS;
    const int* row = ei;
    const int* col = ei + E;

    // workspace layout (4-byte units)
    float*    ws      = (float*)d_ws;
    float*    dinv    = ws;                        // N
    float*    hs      = ws + 512000;               // N*16
    float*    agg     = hs + 8000000;              // N*16
    float*    pooled  = agg + 8000000;             // G*16
    float*    cnt     = pooled + G * 16;           // G
    int*      gcnt    = (int*)(cnt + G);           // NB
    int*      goff    = gcnt + 2048;               // NB+1
    int*      gcursor = goff + 2048;               // NB
    unsigned* packed  = (unsigned*)(gcursor + 2048); // E

    dim3 blk(256);
    int gN = (N + 255) / 256;

    // ---- bucket build ----
    k_filli<<<(NB + 255) / 256, blk, 0, stream>>>(gcnt, 0, NB);
    k_fill<<<(G * 17 + 255) / 256, blk, 0, stream>>>(pooled, 0.0f, G * 17);
    k_bcount<<<NTB, blk, 0, stream>>>(col, gcnt, E);
    k_bscan<<<1, blk, 0, stream>>>(gcnt, goff, gcursor);
    k_bscatter<<<NTB, blk, 0, stream>>>(row, col, gcursor, packed, E);
    k_deg<<<NB, blk, 0, stream>>>(packed, goff, dinv, N);

    // ---- layer 1 ----
    k_l1<<<gN, blk, 0, stream>>>(x, W1, dinv, hs, N);
    k_agg<<<NB, blk, 0, stream>>>(packed, goff, hs, agg, N);

    // ---- layer 2 ----
    k_l2<<<gN, blk, 0, stream>>>(W2, b1, dinv, agg, hs, N);
    k_agg<<<NB, blk, 0, stream>>>(packed, goff, hs, agg, N);

    // ---- pool + head ----
    int chunks = (N + POOL_CH - 1) / POOL_CH;
    int gPool = (chunks * 16 + 255) / 256;
    k_pool2<<<gPool, blk, 0, stream>>>(agg, dinv, b2, batch, pooled, cnt, N);
    k_head<<<(G + 255) / 256, blk, 0, stream>>>(pooled, cnt, meta, Wh1, bh1, Wh2, bh2, out, G);
}

// Round 5
// 731.103 us; speedup vs baseline: 2.4398x; 2.4398x over previous
//
#include <hip/hip_runtime.h>

#define N_NODES 500000
#define N_EDGES 8000000
#define N_GRAPHS 8192
#define POOL_CH 128
#define BKT 256                 // nodes per bucket
#define NB 1954                 // ceil(N_NODES / BKT)
#define TILE_E 16384            // edges per block in bucketing passes
#define NTB 489                 // ceil(N_EDGES / TILE_E)

// ---------------- utility ----------------
__global__ void k_fill(float* __restrict__ p, float v, int n) {
    int i = blockIdx.x * 256 + threadIdx.x;
    if (i < n) p[i] = v;
}
__global__ void k_filli(int* __restrict__ p, int v, int n) {
    int i = blockIdx.x * 256 + threadIdx.x;
    if (i < n) p[i] = v;
}

// ---- pass A: per-bucket edge counts (LDS histogram) ----
__global__ void k_bcount(const int* __restrict__ col, int* __restrict__ gcnt, int E) {
    __shared__ int lcnt[NB];
    int t = threadIdx.x;
    for (int i = t; i < NB; i += 256) lcnt[i] = 0;
    __syncthreads();
    int base = blockIdx.x * TILE_E;
#pragma unroll 4
    for (int k = 0; k < 64; k++) {
        int e = base + k * 256 + t;
        if (e < E) {
            unsigned c = (unsigned)col[e];
            if (c < N_NODES) atomicAdd(&lcnt[c >> 8], 1);
        }
    }
    __syncthreads();
    for (int i = t; i < NB; i += 256)
        if (lcnt[i]) atomicAdd(&gcnt[i], lcnt[i]);
}

// ---- exclusive scan of bucket counts (single block, 256 thr x 8) ----
__global__ void k_bscan(const int* __restrict__ gcnt, int* __restrict__ goff,
                        int* __restrict__ gcursor) {
    __shared__ int sd[256];
    int t = threadIdx.x;
    int v[8]; int s = 0;
    int base = t * 8;
#pragma unroll
    for (int k = 0; k < 8; k++) { int i = base + k; v[k] = (i < NB) ? gcnt[i] : 0; s += v[k]; }
    sd[t] = s; __syncthreads();
    for (int d = 1; d < 256; d <<= 1) {
        int tv = (t >= d) ? sd[t - d] : 0;
        __syncthreads(); sd[t] += tv; __syncthreads();
    }
    int run = sd[t] - s;
#pragma unroll
    for (int k = 0; k < 8; k++) {
        int i = base + k;
        if (i < NB) { goff[i] = run; gcursor[i] = run; run += v[k]; }
    }
    if (t == 255) goff[NB] = run;
}

// ---- pass B: scatter packed (r<<8 | c_local) into bucket-grouped array ----
__global__ void k_bscatter(const int* __restrict__ row, const int* __restrict__ col,
                           int* __restrict__ gcursor, unsigned* __restrict__ packed, int E) {
    __shared__ int lcnt[NB];
    __shared__ int lbase[NB];
    int t = threadIdx.x;
    for (int i = t; i < NB; i += 256) lcnt[i] = 0;
    __syncthreads();
    int base = blockIdx.x * TILE_E;
#pragma unroll 4
    for (int k = 0; k < 64; k++) {
        int e = base + k * 256 + t;
        if (e < E) {
            unsigned c = (unsigned)col[e];
            if (c < N_NODES) atomicAdd(&lcnt[c >> 8], 1);
        }
    }
    __syncthreads();
    for (int i = t; i < NB; i += 256) {
        int c = lcnt[i];
        lbase[i] = c ? atomicAdd(&gcursor[i], c) : 0;
        lcnt[i] = 0;
    }
    __syncthreads();
    for (int k = 0; k < 64; k++) {
        int e = base + k * 256 + t;
        if (e < E) {
            unsigned c = (unsigned)col[e];
            unsigned r = (unsigned)row[e];
            if (c < N_NODES && r < N_NODES) {
                unsigned b = c >> 8;
                int pos = lbase[b] + atomicAdd(&lcnt[b], 1);
                packed[pos] = (r << 8) | (c & 255u);
            }
        }
    }
}

// ---- bucket-grouped packed -> CSR (srcs sorted by target) + rowptr + dinv ----
// Scattered srcs writes stay inside this bucket's ~16KB window: L2-resident,
// lines fully collected before eviction (unlike R2's k_fillidx 32MB window).
__global__ void k_csr(const unsigned* __restrict__ packed, const int* __restrict__ goff,
                      int* __restrict__ srcs, int* __restrict__ rowptr,
                      float* __restrict__ dinv, int N) {
    __shared__ int hist[BKT];
    __shared__ int sc[BKT];
    __shared__ int off[BKT];
    int t = threadIdx.x;
    int b = blockIdx.x;
    int s = goff[b], e = goff[b + 1];
    int cnt = e - s;
    hist[t] = 0;
    __syncthreads();
    for (int i = t; i < cnt; i += 256)
        atomicAdd(&hist[packed[s + i] & 255u], 1);
    __syncthreads();
    int h = hist[t];
    sc[t] = h; __syncthreads();
    for (int d = 1; d < 256; d <<= 1) {
        int tv = (t >= d) ? sc[t - d] : 0;
        __syncthreads(); sc[t] += tv; __syncthreads();
    }
    off[t] = sc[t] - h;   // exclusive prefix within bucket
    int v = b * BKT + t;
    if (v < N) {
        rowptr[v] = s + off[t];
        dinv[v] = rsqrtf(1.0f + (float)h);
    }
    if (b == NB - 1 && t == 0) rowptr[N] = e;
    hist[t] = 0;   // reuse as per-node cursor
    __syncthreads();
    for (int i = t; i < cnt; i += 256) {
        unsigned w = packed[s + i];
        unsigned c = w & 255u;
        int p = off[c] + atomicAdd(&hist[c], 1);
        srcs[s + p] = (int)(w >> 8);
    }
}

// ---- layer-1 node transform: hs = (x @ W1) * dinv ----
__global__ void k_l1(const float* __restrict__ x, const float* __restrict__ W1,
                     const float* __restrict__ dinv, float* __restrict__ hs, int n) {
    int v = blockIdx.x * 256 + threadIdx.x;
    if (v >= n) return;
    float xi[9];
#pragma unroll
    for (int k = 0; k < 9; k++) xi[k] = x[v * 9 + k];
    float di = dinv[v];
#pragma unroll
    for (int j = 0; j < 16; j++) {
        float acc = 0.f;
#pragma unroll
        for (int k = 0; k < 9; k++) acc += xi[k] * W1[k * 16 + j];
        hs[v * 16 + j] = acc * di;
    }
}

// ---- pull layer 1 with fused layer-2 node transform ----
// agg = hs[v] + sum_{r in in(v)} hs[r]  (16 lanes/node, unroll-4 gathers)
// then h1 = relu(agg*dinv + b1); hs2 = (h1 @ W2) * dinv via 16-lane shfl
__global__ void k_pullA(const int* __restrict__ rowptr, const int* __restrict__ srcs,
                        const float* __restrict__ hs, const float* __restrict__ dinv,
                        const float* __restrict__ b1, const float* __restrict__ W2,
                        float* __restrict__ hs2, int N) {
    int tid = blockIdx.x * 256 + threadIdx.x;
    int v = tid >> 4;
    int j = tid & 15;
    if (v >= N) return;
    int s = rowptr[v], e = rowptr[v + 1];
    float acc = hs[v * 16 + j];
    int k = s;
    for (; k + 4 <= e; k += 4) {
        int r0 = srcs[k], r1 = srcs[k + 1], r2 = srcs[k + 2], r3 = srcs[k + 3];
        float a0 = hs[r0 * 16 + j];
        float a1 = hs[r1 * 16 + j];
        float a2 = hs[r2 * 16 + j];
        float a3 = hs[r3 * 16 + j];
        acc += a0 + a1 + a2 + a3;
    }
    for (; k < e; k++) acc += hs[srcs[k] * 16 + j];
    float di = dinv[v];
    float h1 = acc * di + b1[j];
    h1 = h1 > 0.f ? h1 : 0.f;
    float o = 0.f;
#pragma unroll
    for (int kk = 0; kk < 16; kk++) {
        float hk = __shfl(h1, kk, 16);
        o += hk * W2[kk * 16 + j];
    }
    hs2[v * 16 + j] = o * di;
}

// ---- pull layer 2: agg2 = hs2[v] + sum hs2[r] ----
__global__ void k_pullB(const int* __restrict__ rowptr, const int* __restrict__ srcs,
                        const float* __restrict__ hs2, float* __restrict__ agg, int N) {
    int tid = blockIdx.x * 256 + threadIdx.x;
    int v = tid >> 4;
    int j = tid & 15;
    if (v >= N) return;
    int s = rowptr[v], e = rowptr[v + 1];
    float acc = hs2[v * 16 + j];
    int k = s;
    for (; k + 4 <= e; k += 4) {
        int r0 = srcs[k], r1 = srcs[k + 1], r2 = srcs[k + 2], r3 = srcs[k + 3];
        float a0 = hs2[r0 * 16 + j];
        float a1 = hs2[r1 * 16 + j];
        float a2 = hs2[r2 * 16 + j];
        float a3 = hs2[r3 * 16 + j];
        acc += a0 + a1 + a2 + a3;
    }
    for (; k < e; k++) acc += hs2[srcs[k] * 16 + j];
    agg[v * 16 + j] = acc;
}

// ---- pool exploiting sorted batch ----
__global__ void k_pool2(const float* __restrict__ agg, const float* __restrict__ dinv,
                        const float* __restrict__ b2, const int* __restrict__ batch,
                        float* __restrict__ pooled, float* __restrict__ cnt, int n) {
    int tid = blockIdx.x * 256 + threadIdx.x;
    int chunk = tid >> 4;
    int j = tid & 15;
    int start = chunk * POOL_CH;
    if (start >= n) return;
    int end = start + POOL_CH;
    if (end > n) end = n;
    float bj = b2[j];
    int g_cur = batch[start];
    float acc = 0.f;
    float c_acc = 0.f;
    for (int v = start; v < end; v++) {
        int g = batch[v];
        if (g != g_cur) {
            atomicAdd(&pooled[g_cur * 16 + j], acc);
            if (j == 0) atomicAdd(&cnt[g_cur], c_acc);
            acc = 0.f; c_acc = 0.f; g_cur = g;
        }
        float t = agg[v * 16 + j] * dinv[v] + bj;
        acc += t > 0.f ? t : 0.f;
        c_acc += 1.f;
    }
    atomicAdd(&pooled[g_cur * 16 + j], acc);
    if (j == 0) atomicAdd(&cnt[g_cur], c_acc);
}

// ---- head MLP ----
__global__ void k_head(const float* __restrict__ pooled, const float* __restrict__ cnt,
                       const float* __restrict__ meta, const float* __restrict__ Wh1,
                       const float* __restrict__ bh1, const float* __restrict__ Wh2,
                       const float* __restrict__ bh2, float* __restrict__ out, int G) {
    int g = blockIdx.x * 256 + threadIdx.x;
    if (g >= G) return;
    float z[43];
    float c = cnt[g];
    c = c > 1.f ? c : 1.f;
#pragma unroll
    for (int j = 0; j < 16; j++) z[j] = pooled[g * 16 + j] / c;
#pragma unroll
    for (int j = 0; j < 27; j++) z[16 + j] = meta[g * 27 + j];
    float acc2 = bh2[0];
#pragma unroll
    for (int jj = 0; jj < 16; jj++) {
        float a = bh1[jj];
#pragma unroll
        for (int k = 0; k < 43; k++) a += z[k] * Wh1[k * 16 + jj];
        a = a > 0.f ? a : 0.f;
        acc2 += a * Wh2[jj];
    }
    out[g] = acc2;
}

extern "C" void kernel_launch(void* const* d_in, const int* in_sizes, int n_in,
                              void* d_out, int out_size, void* d_ws, size_t ws_size,
                              hipStream_t stream) {
    const float* x    = (const float*)d_in[0];
    const int*   ei   = (const int*)d_in[1];   // [2, E]: row then col
    const int*   batch= (const int*)d_in[2];
    const float* meta = (const float*)d_in[3];
    const float* W1   = (const float*)d_in[4];
    const float* b1   = (const float*)d_in[5];
    const float* W2   = (const float*)d_in[6];
    const float* b2   = (const float*)d_in[7];
    const float* Wh1  = (const float*)d_in[8];
    const float* bh1  = (const float*)d_in[9];
    const float* Wh2  = (const float*)d_in[10];
    const float* bh2  = (const float*)d_in[11];
    float* out = (float*)d_out;

    const int N = N_NODES, E = N_EDGES, G = N_GRAPHS;
    const int* row = ei;
    const int* col = ei + E;

    // workspace layout (4-byte units). packed aliases hs/agg: packed is dead
    // after k_csr, before k_l1 writes hs.
    float*    ws      = (float*)d_ws;
    float*    dinv    = ws;                          // N
    float*    hs      = ws + 512000;                 // N*16 (also: packed, agg)
    float*    hs2     = hs + 8000000;                // N*16
    int*      srcs    = (int*)(hs2 + 8000000);       // E
    float*    pooled  = (float*)(srcs + 8000000);    // G*16
    float*    cnt     = pooled + G * 16;             // G
    int*      gcnt    = (int*)(cnt + G);             // NB
    int*      goff    = gcnt + 2048;                 // NB+1
    int*      gcursor = goff + 2048;                 // NB
    int*      rowptr  = gcursor + 2048;              // N+1
    unsigned* packed  = (unsigned*)hs;               // E (alias)
    float*    agg     = hs;                          // alias (hs dead after pullA)

    dim3 blk(256);
    int gN = (N + 255) / 256;

    // ---- bucket build + CSR ----
    k_filli<<<(NB + 255) / 256, blk, 0, stream>>>(gcnt, 0, NB);
    k_fill<<<(G * 17 + 255) / 256, blk, 0, stream>>>(pooled, 0.0f, G * 17);
    k_bcount<<<NTB, blk, 0, stream>>>(col, gcnt, E);
    k_bscan<<<1, blk, 0, stream>>>(gcnt, goff, gcursor);
    k_bscatter<<<NTB, blk, 0, stream>>>(row, col, gcursor, packed, E);
    k_csr<<<NB, blk, 0, stream>>>(packed, goff, srcs, rowptr, dinv, N);

    // ---- layer 1 (+fused layer-2 transform) ----
    k_l1<<<gN, blk, 0, stream>>>(x, W1, dinv, hs, N);
    int gP16 = (N * 16 + 255) / 256;
    k_pullA<<<gP16, blk, 0, stream>>>(rowptr, srcs, hs, dinv, b1, W2, hs2, N);

    // ---- layer 2 aggregation ----
    k_pullB<<<gP16, blk, 0, stream>>>(rowptr, srcs, hs2, agg, N);

    // ---- pool + head ----
    int chunks = (N + POOL_CH - 1) / POOL_CH;
    int gPool = (chunks * 16 + 255) / 256;
    k_pool2<<<gPool, blk, 0, stream>>>(agg, dinv, b2, batch, pooled, cnt, N);
    k_head<<<(G + 255) / 256, blk, 0, stream>>>(pooled, cnt, meta, Wh1, bh1, Wh2, bh2, out, G);
}

// Round 7
// 728.970 us; speedup vs baseline: 2.4470x; 1.0029x over previous
//
#include <hip/hip_runtime.h>

#define N_NODES 500000
#define N_EDGES 8000000
#define N_GRAPHS 8192
#define POOL_CH 128
#define BKT 256                 // nodes per bucket
#define NB 1954                 // ceil(N_NODES / BKT)
#define TILE_E 16384            // edges per block in bucketing passes
#define NTB 489                 // ceil(N_EDGES / TILE_E)

// ---------------- utility ----------------
__global__ void k_fill(float* __restrict__ p, float v, int n) {
    int i = blockIdx.x * 256 + threadIdx.x;
    if (i < n) p[i] = v;
}

// ---- pass A: per-block per-bucket counts -> cntmat[block][bucket] ----
__global__ void k_bcount2(const int4* __restrict__ col4, int* __restrict__ cntmat, int E) {
    __shared__ int lcnt[NB];
    int t = threadIdx.x;
    int b = blockIdx.x;
    for (int i = t; i < NB; i += 256) lcnt[i] = 0;
    __syncthreads();
#pragma unroll 4
    for (int k = 0; k < 16; k++) {
        int vi = b * 4096 + k * 256 + t;
        int e0 = vi * 4;
        if (e0 < E) {
            int4 c = col4[vi];
            if ((unsigned)c.x < N_NODES) atomicAdd(&lcnt[(unsigned)c.x >> 8], 1);
            if (e0 + 1 < E && (unsigned)c.y < N_NODES) atomicAdd(&lcnt[(unsigned)c.y >> 8], 1);
            if (e0 + 2 < E && (unsigned)c.z < N_NODES) atomicAdd(&lcnt[(unsigned)c.z >> 8], 1);
            if (e0 + 3 < E && (unsigned)c.w < N_NODES) atomicAdd(&lcnt[(unsigned)c.w >> 8], 1);
        }
    }
    __syncthreads();
    for (int i = t; i < NB; i += 256) cntmat[b * NB + i] = lcnt[i];
}

// ---- column-scan of cntmat: cntmat[r][b] becomes exclusive prefix over r;
//      gcnt[b] = total. Coalesced (consecutive threads = consecutive buckets).
__global__ void k_mscan(int* __restrict__ cntmat, int* __restrict__ gcnt) {
    int b = blockIdx.x * 256 + threadIdx.x;
    if (b >= NB) return;
    int run = 0;
#pragma unroll 8
    for (int r = 0; r < NTB; r++) {
        int v = cntmat[r * NB + b];
        cntmat[r * NB + b] = run;
        run += v;
    }
    gcnt[b] = run;
}

// ---- exclusive scan of bucket totals -> goff ----
__global__ void k_bscan(const int* __restrict__ gcnt, int* __restrict__ goff) {
    __shared__ int sd[256];
    int t = threadIdx.x;
    int v[8]; int s = 0;
    int base = t * 8;
#pragma unroll
    for (int k = 0; k < 8; k++) { int i = base + k; v[k] = (i < NB) ? gcnt[i] : 0; s += v[k]; }
    sd[t] = s; __syncthreads();
    for (int d = 1; d < 256; d <<= 1) {
        int tv = (t >= d) ? sd[t - d] : 0;
        __syncthreads(); sd[t] += tv; __syncthreads();
    }
    int run = sd[t] - s;
#pragma unroll
    for (int k = 0; k < 8; k++) {
        int i = base + k;
        if (i < NB) { goff[i] = run; run += v[k]; }
    }
    if (t == 255) goff[NB] = run;
}

// ---- single-pass scatter: cursors = goff + cntmat row, then scatter ----
__global__ void k_bscatter2(const int4* __restrict__ row4, const int4* __restrict__ col4,
                            const int* __restrict__ goff, const int* __restrict__ cntmat,
                            unsigned* __restrict__ packed, int E) {
    __shared__ int lcur[NB];
    int t = threadIdx.x;
    int b = blockIdx.x;
    for (int i = t; i < NB; i += 256) lcur[i] = goff[i] + cntmat[b * NB + i];
    __syncthreads();
#pragma unroll 2
    for (int k = 0; k < 16; k++) {
        int vi = b * 4096 + k * 256 + t;
        int e0 = vi * 4;
        if (e0 < E) {
            int4 c = col4[vi];
            int4 r = row4[vi];
            {
                unsigned cc = (unsigned)c.x, rr = (unsigned)r.x;
                if (cc < N_NODES && rr < N_NODES) {
                    int pos = atomicAdd(&lcur[cc >> 8], 1);
                    packed[pos] = (rr << 8) | (cc & 255u);
                }
            }
            if (e0 + 1 < E) {
                unsigned cc = (unsigned)c.y, rr = (unsigned)r.y;
                if (cc < N_NODES && rr < N_NODES) {
                    int pos = atomicAdd(&lcur[cc >> 8], 1);
                    packed[pos] = (rr << 8) | (cc & 255u);
                }
            }
            if (e0 + 2 < E) {
                unsigned cc = (unsigned)c.z, rr = (unsigned)r.z;
                if (cc < N_NODES && rr < N_NODES) {
                    int pos = atomicAdd(&lcur[cc >> 8], 1);
                    packed[pos] = (rr << 8) | (cc & 255u);
                }
            }
            if (e0 + 3 < E) {
                unsigned cc = (unsigned)c.w, rr = (unsigned)r.w;
                if (cc < N_NODES && rr < N_NODES) {
                    int pos = atomicAdd(&lcur[cc >> 8], 1);
                    packed[pos] = (rr << 8) | (cc & 255u);
                }
            }
        }
    }
}

// ---- bucket-grouped packed -> CSR (srcs sorted by target) + rowptr + dinv ----
__global__ void k_csr(const unsigned* __restrict__ packed, const int* __restrict__ goff,
                      int* __restrict__ srcs, int* __restrict__ rowptr,
                      float* __restrict__ dinv, int N) {
    __shared__ int hist[BKT];
    __shared__ int sc[BKT];
    __shared__ int off[BKT];
    int t = threadIdx.x;
    int b = blockIdx.x;
    int s = goff[b], e = goff[b + 1];
    int cnt = e - s;
    hist[t] = 0;
    __syncthreads();
    for (int i = t; i < cnt; i += 256)
        atomicAdd(&hist[packed[s + i] & 255u], 1);
    __syncthreads();
    int h = hist[t];
    sc[t] = h; __syncthreads();
    for (int d = 1; d < 256; d <<= 1) {
        int tv = (t >= d) ? sc[t - d] : 0;
        __syncthreads(); sc[t] += tv; __syncthreads();
    }
    off[t] = sc[t] - h;
    int v = b * BKT + t;
    if (v < N) {
        rowptr[v] = s + off[t];
        dinv[v] = rsqrtf(1.0f + (float)h);
    }
    if (b == NB - 1 && t == 0) rowptr[N] = e;
    hist[t] = 0;   // reuse as per-node cursor
    __syncthreads();
    for (int i = t; i < cnt; i += 256) {
        unsigned w = packed[s + i];
        unsigned c = w & 255u;
        int p = off[c] + atomicAdd(&hist[c], 1);
        srcs[s + p] = (int)(w >> 8);
    }
}

// ---- layer-1 node transform: hs = (x @ W1) * dinv ----
__global__ void k_l1(const float* __restrict__ x, const float* __restrict__ W1,
                     const float* __restrict__ dinv, float* __restrict__ hs, int n) {
    int v = blockIdx.x * 256 + threadIdx.x;
    if (v >= n) return;
    float xi[9];
#pragma unroll
    for (int k = 0; k < 9; k++) xi[k] = x[v * 9 + k];
    float di = dinv[v];
#pragma unroll
    for (int j = 0; j < 16; j++) {
        float acc = 0.f;
#pragma unroll
        for (int k = 0; k < 9; k++) acc += xi[k] * W1[k * 16 + j];
        hs[v * 16 + j] = acc * di;
    }
}

// ---- pull layer 1 (float4: 4 lanes/node) + fused layer-2 node transform ----
__global__ void k_pullA(const int* __restrict__ rowptr, const int* __restrict__ srcs,
                        const float4* __restrict__ hs4, const float* __restrict__ dinv,
                        const float4* __restrict__ b14, const float4* __restrict__ W24,
                        float4* __restrict__ hs24, int N) {
    int tid = blockIdx.x * 256 + threadIdx.x;
    int v = tid >> 2;
    int q = tid & 3;          // which float4 of the 16 features
    if (v >= N) return;
    int s = rowptr[v], e = rowptr[v + 1];
    float4 acc = hs4[v * 4 + q];   // self loop
    int k = s;
    for (; k + 4 <= e; k += 4) {
        int r0 = srcs[k], r1 = srcs[k + 1], r2 = srcs[k + 2], r3 = srcs[k + 3];
        float4 a0 = hs4[r0 * 4 + q];
        float4 a1 = hs4[r1 * 4 + q];
        float4 a2 = hs4[r2 * 4 + q];
        float4 a3 = hs4[r3 * 4 + q];
        acc.x += a0.x + a1.x + a2.x + a3.x;
        acc.y += a0.y + a1.y + a2.y + a3.y;
        acc.z += a0.z + a1.z + a2.z + a3.z;
        acc.w += a0.w + a1.w + a2.w + a3.w;
    }
    for (; k < e; k++) {
        float4 a = hs4[srcs[k] * 4 + q];
        acc.x += a.x; acc.y += a.y; acc.z += a.z; acc.w += a.w;
    }
    float di = dinv[v];
    float4 bb = b14[q];
    float h1[4];
    h1[0] = acc.x * di + bb.x; h1[0] = h1[0] > 0.f ? h1[0] : 0.f;
    h1[1] = acc.y * di + bb.y; h1[1] = h1[1] > 0.f ? h1[1] : 0.f;
    h1[2] = acc.z * di + bb.z; h1[2] = h1[2] > 0.f ? h1[2] : 0.f;
    h1[3] = acc.w * di + bb.w; h1[3] = h1[3] > 0.f ? h1[3] : 0.f;
    float4 o = make_float4(0.f, 0.f, 0.f, 0.f);
#pragma unroll
    for (int kk = 0; kk < 16; kk++) {
        float hk = __shfl(h1[kk & 3], kk >> 2, 4);
        float4 w = W24[kk * 4 + q];   // W2[kk][4q..4q+3]
        o.x += hk * w.x; o.y += hk * w.y; o.z += hk * w.z; o.w += hk * w.w;
    }
    o.x *= di; o.y *= di; o.z *= di; o.w *= di;
    hs24[v * 4 + q] = o;
}

// ---- pull layer 2 (float4): agg = hs2[v] + sum hs2[r] ----
__global__ void k_pullB(const int* __restrict__ rowptr, const int* __restrict__ srcs,
                        const float4* __restrict__ hs24, float4* __restrict__ agg4, int N) {
    int tid = blockIdx.x * 256 + threadIdx.x;
    int v = tid >> 2;
    int q = tid & 3;
    if (v >= N) return;
    int s = rowptr[v], e = rowptr[v + 1];
    float4 acc = hs24[v * 4 + q];
    int k = s;
    for (; k + 4 <= e; k += 4) {
        int r0 = srcs[k], r1 = srcs[k + 1], r2 = srcs[k + 2], r3 = srcs[k + 3];
        float4 a0 = hs24[r0 * 4 + q];
        float4 a1 = hs24[r1 * 4 + q];
        float4 a2 = hs24[r2 * 4 + q];
        float4 a3 = hs24[r3 * 4 + q];
        acc.x += a0.x + a1.x + a2.x + a3.x;
        acc.y += a0.y + a1.y + a2.y + a3.y;
        acc.z += a0.z + a1.z + a2.z + a3.z;
        acc.w += a0.w + a1.w + a2.w + a3.w;
    }
    for (; k < e; k++) {
        float4 a = hs24[srcs[k] * 4 + q];
        acc.x += a.x; acc.y += a.y; acc.z += a.z; acc.w += a.w;
    }
    agg4[v * 4 + q] = acc;
}

// ---- pool exploiting sorted batch ----
__global__ void k_pool2(const float* __restrict__ agg, const float* __restrict__ dinv,
                        const float* __restrict__ b2, const int* __restrict__ batch,
                        float* __restrict__ pooled, float* __restrict__ cnt, int n) {
    int tid = blockIdx.x * 256 + threadIdx.x;
    int chunk = tid >> 4;
    int j = tid & 15;
    int start = chunk * POOL_CH;
    if (start >= n) return;
    int end = start + POOL_CH;
    if (end > n) end = n;
    float bj = b2[j];
    int g_cur = batch[start];
    float acc = 0.f;
    float c_acc = 0.f;
    for (int v = start; v < end; v++) {
        int g = batch[v];
        if (g != g_cur) {
            atomicAdd(&pooled[g_cur * 16 + j], acc);
            if (j == 0) atomicAdd(&cnt[g_cur], c_acc);
            acc = 0.f; c_acc = 0.f; g_cur = g;
        }
        float t = agg[v * 16 + j] * dinv[v] + bj;
        acc += t > 0.f ? t : 0.f;
        c_acc += 1.f;
    }
    atomicAdd(&pooled[g_cur * 16 + j], acc);
    if (j == 0) atomicAdd(&cnt[g_cur], c_acc);
}

// ---- head MLP ----
__global__ void k_head(const float* __restrict__ pooled, const float* __restrict__ cnt,
                       const float* __restrict__ meta, const float* __restrict__ Wh1,
                       const float* __restrict__ bh1, const float* __restrict__ Wh2,
                       const float* __restrict__ bh2, float* __restrict__ out, int G) {
    int g = blockIdx.x * 256 + threadIdx.x;
    if (g >= G) return;
    float z[43];
    float c = cnt[g];
    c = c > 1.f ? c : 1.f;
#pragma unroll
    for (int j = 0; j < 16; j++) z[j] = pooled[g * 16 + j] / c;
#pragma unroll
    for (int j = 0; j < 27; j++) z[16 + j] = meta[g * 27 + j];
    float acc2 = bh2[0];
#pragma unroll
    for (int jj = 0; jj < 16; jj++) {
        float a = bh1[jj];
#pragma unroll
        for (int k = 0; k < 43; k++) a += z[k] * Wh1[k * 16 + jj];
        a = a > 0.f ? a : 0.f;
        acc2 += a * Wh2[jj];
    }
    out[g] = acc2;
}

extern "C" void kernel_launch(void* const* d_in, const int* in_sizes, int n_in,
                              void* d_out, int out_size, void* d_ws, size_t ws_size,
                              hipStream_t stream) {
    const float* x    = (const float*)d_in[0];
    const int*   ei   = (const int*)d_in[1];   // [2, E]: row then col
    const int*   batch= (const int*)d_in[2];
    const float* meta = (const float*)d_in[3];
    const float* W1   = (const float*)d_in[4];
    const float* b1   = (const float*)d_in[5];
    const float* W2   = (const float*)d_in[6];
    const float* b2   = (const float*)d_in[7];
    const float* Wh1  = (const float*)d_in[8];
    const float* bh1  = (const float*)d_in[9];
    const float* Wh2  = (const float*)d_in[10];
    const float* bh2  = (const float*)d_in[11];
    float* out = (float*)d_out;

    const int N = N_NODES, E = N_EDGES, G = N_GRAPHS;
    const int* row = ei;
    const int* col = ei + E;

    // workspace layout (4-byte units). packed aliases hs (dead before k_l1);
    // agg aliases hs (hs dead after pullA).
    float*    ws      = (float*)d_ws;
    float*    dinv    = ws;                          // N (pad to 512000)
    float*    hs      = ws + 512000;                 // N*16 (alias: packed, agg)
    float*    hs2     = hs + 8000000;                // N*16
    int*      srcs    = (int*)(hs2 + 8000000);       // E
    float*    pooled  = (float*)(srcs + 8000000);    // G*16
    float*    cnt     = pooled + G * 16;             // G
    int*      gcnt    = (int*)(cnt + G);             // NB (pad 2048)
    int*      goff    = gcnt + 2048;                 // NB+1 (pad 2048)
    int*      rowptr  = goff + 2048;                 // N+1 (pad 512064)
    int*      cntmat  = rowptr + 512064;             // NTB*NB = 955506
    unsigned* packed  = (unsigned*)hs;               // E (alias)
    float*    agg     = hs;                          // alias

    dim3 blk(256);
    int gN = (N + 255) / 256;

    // ---- bucket build + CSR ----
    k_fill<<<(G * 17 + 255) / 256, blk, 0, stream>>>(pooled, 0.0f, G * 17);
    k_bcount2<<<NTB, blk, 0, stream>>>((const int4*)col, cntmat, E);
    k_mscan<<<(NB + 255) / 256, blk, 0, stream>>>(cntmat, gcnt);
    k_bscan<<<1, blk, 0, stream>>>(gcnt, goff);
    k_bscatter2<<<NTB, blk, 0, stream>>>((const int4*)row, (const int4*)col,
                                         goff, cntmat, packed, E);
    k_csr<<<NB, blk, 0, stream>>>(packed, goff, srcs, rowptr, dinv, N);

    // ---- layer 1 (+fused layer-2 transform) ----
    k_l1<<<gN, blk, 0, stream>>>(x, W1, dinv, hs, N);
    int gP4 = (N * 4 + 255) / 256;
    k_pullA<<<gP4, blk, 0, stream>>>(rowptr, srcs, (const float4*)hs, dinv,
                                     (const float4*)b1, (const float4*)W2,
                                     (float4*)hs2, N);

    // ---- layer 2 aggregation ----
    k_pullB<<<gP4, blk, 0, stream>>>(rowptr, srcs, (const float4*)hs2, (float4*)agg, N);

    // ---- pool + head ----
    int chunks = (N + POOL_CH - 1) / POOL_CH;
    int gPool = (chunks * 16 + 255) / 256;
    k_pool2<<<gPool, blk, 0, stream>>>(agg, dinv, b2, batch, pooled, cnt, N);
    k_head<<<(G + 255) / 256, blk, 0, stream>>>(pooled, cnt, meta, Wh1, bh1, Wh2, bh2, out, G);
}

// Round 8
// 656.535 us; speedup vs baseline: 2.7169x; 1.1103x over previous
//
#include <hip/hip_runtime.h>

#define N_NODES 500000
#define N_EDGES 8000000
#define N_GRAPHS 8192
#define POOL_CH 128
#define BKT 1024                // nodes per bucket
#define NB 489                  // ceil(N_NODES / BKT)
#define C_CAP 18432             // fixed capacity per bucket (mean 16384, +16 sigma)
#define TILE2 8192              // edges per build block
#define NTB2 977                // ceil(N_EDGES / TILE2)

// ---------------- utility ----------------
__global__ void k_fill(float* __restrict__ p, float v, int n) {
    int i = blockIdx.x * 256 + threadIdx.x;
    if (i < n) p[i] = v;
}

__global__ void k_initcur(int* __restrict__ gcursor) {
    int i = blockIdx.x * 256 + threadIdx.x;
    if (i < NB) gcursor[i] = i * C_CAP;
}

// ---- one-pass bucket build: read edges once, stage in LDS, claim runs ----
__global__ void k_build(const int4* __restrict__ row4, const int4* __restrict__ col4,
                        int* __restrict__ gcursor, unsigned* __restrict__ packed, int E) {
    __shared__ unsigned stage[TILE2];          // 32 KB: (r<<10)|(c&1023)
    __shared__ unsigned short bkt[TILE2];      // 16 KB: bucket id (0xFFFF = invalid)
    __shared__ int hist[NB];                   // ~2 KB
    __shared__ int runbase[NB];                // ~2 KB
    int t = threadIdx.x, b = blockIdx.x;
    for (int i = t; i < NB; i += 256) hist[i] = 0;
    __syncthreads();
#pragma unroll
    for (int k = 0; k < 8; k++) {
        int li4 = k * 256 + t;                 // 0..2047
        int vi = b * 2048 + li4;
        int idx = li4 * 4;
        if (vi * 4 < E) {                      // E % 4 == 0: whole int4 valid
            int4 c = col4[vi];
            int4 r = row4[vi];
            unsigned cc, rr;
            cc = (unsigned)c.x; rr = (unsigned)r.x;
            if (cc < N_NODES && rr < N_NODES) { stage[idx] = (rr << 10) | (cc & 1023u); bkt[idx] = (unsigned short)(cc >> 10); atomicAdd(&hist[cc >> 10], 1); } else bkt[idx] = 0xFFFFu;
            cc = (unsigned)c.y; rr = (unsigned)r.y;
            if (cc < N_NODES && rr < N_NODES) { stage[idx+1] = (rr << 10) | (cc & 1023u); bkt[idx+1] = (unsigned short)(cc >> 10); atomicAdd(&hist[cc >> 10], 1); } else bkt[idx+1] = 0xFFFFu;
            cc = (unsigned)c.z; rr = (unsigned)r.z;
            if (cc < N_NODES && rr < N_NODES) { stage[idx+2] = (rr << 10) | (cc & 1023u); bkt[idx+2] = (unsigned short)(cc >> 10); atomicAdd(&hist[cc >> 10], 1); } else bkt[idx+2] = 0xFFFFu;
            cc = (unsigned)c.w; rr = (unsigned)r.w;
            if (cc < N_NODES && rr < N_NODES) { stage[idx+3] = (rr << 10) | (cc & 1023u); bkt[idx+3] = (unsigned short)(cc >> 10); atomicAdd(&hist[cc >> 10], 1); } else bkt[idx+3] = 0xFFFFu;
        } else {
            bkt[idx] = 0xFFFFu; bkt[idx+1] = 0xFFFFu; bkt[idx+2] = 0xFFFFu; bkt[idx+3] = 0xFFFFu;
        }
    }
    __syncthreads();
    for (int i = t; i < NB; i += 256) {
        int c = hist[i];
        runbase[i] = c ? atomicAdd(&gcursor[i], c) : 0;
        hist[i] = 0;                            // reuse as local cursor
    }
    __syncthreads();
    for (int i = t; i < TILE2; i += 256) {
        unsigned bb = bkt[i];
        if (bb != 0xFFFFu) {
            int pos = runbase[bb] + atomicAdd(&hist[bb], 1);
            packed[pos] = stage[i];
        }
    }
}

// ---- end-cursors -> compact exclusive offsets goff[NB+1] (single block) ----
__global__ void k_cnt2off(const int* __restrict__ gcursor, int* __restrict__ goff) {
    __shared__ int sd[256];
    int t = threadIdx.x;
    int v[2]; int s = 0;
#pragma unroll
    for (int k = 0; k < 2; k++) {
        int i = t * 2 + k;
        v[k] = (i < NB) ? (gcursor[i] - i * C_CAP) : 0;
        s += v[k];
    }
    sd[t] = s; __syncthreads();
    for (int d = 1; d < 256; d <<= 1) {
        int tv = (t >= d) ? sd[t - d] : 0;
        __syncthreads(); sd[t] += tv; __syncthreads();
    }
    int run = sd[t] - s;
#pragma unroll
    for (int k = 0; k < 2; k++) {
        int i = t * 2 + k;
        if (i < NB) goff[i] = run;
        run += v[k];
    }
    if (t == 255) goff[NB] = sd[255];
}

// ---- per-bucket packed -> compact CSR (srcs sorted by target) + rowptr + dinv
__global__ void k_csr(const unsigned* __restrict__ packed, const int* __restrict__ goff,
                      int* __restrict__ srcs, int* __restrict__ rowptr,
                      float* __restrict__ dinv, int N) {
    __shared__ int hist[BKT];   // 4 KB
    __shared__ int off[BKT];    // 4 KB
    __shared__ int sd[256];
    int t = threadIdx.x, b = blockIdx.x;
    int gbase = goff[b];
    int cnt = goff[b + 1] - gbase;
    int sfix = b * C_CAP;
    for (int k = t; k < BKT; k += 256) hist[k] = 0;
    __syncthreads();
    for (int i = t; i < cnt; i += 256)
        atomicAdd(&hist[packed[sfix + i] & 1023u], 1);
    __syncthreads();
    int ls[4]; int s = 0;
#pragma unroll
    for (int k = 0; k < 4; k++) { ls[k] = hist[t * 4 + k]; s += ls[k]; }
    sd[t] = s; __syncthreads();
    for (int d = 1; d < 256; d <<= 1) {
        int tv = (t >= d) ? sd[t - d] : 0;
        __syncthreads(); sd[t] += tv; __syncthreads();
    }
    int run = sd[t] - s;
#pragma unroll
    for (int k = 0; k < 4; k++) {
        off[t * 4 + k] = run;
        int v = b * BKT + t * 4 + k;
        if (v < N) {
            rowptr[v] = gbase + run;
            dinv[v] = rsqrtf(1.0f + (float)ls[k]);
        }
        run += ls[k];
    }
    if (b == NB - 1 && t == 255) rowptr[N] = gbase + run;
    __syncthreads();
    for (int k = t; k < BKT; k += 256) hist[k] = 0;   // reuse as per-node cursor
    __syncthreads();
    for (int i = t; i < cnt; i += 256) {
        unsigned w = packed[sfix + i];
        unsigned c = w & 1023u;
        int p = off[c] + atomicAdd(&hist[c], 1);
        srcs[gbase + p] = (int)(w >> 10);
    }
}

// ---- layer-1 node transform: hs = (x @ W1) * dinv ----
__global__ void k_l1(const float* __restrict__ x, const float* __restrict__ W1,
                     const float* __restrict__ dinv, float* __restrict__ hs, int n) {
    int v = blockIdx.x * 256 + threadIdx.x;
    if (v >= n) return;
    float xi[9];
#pragma unroll
    for (int k = 0; k < 9; k++) xi[k] = x[v * 9 + k];
    float di = dinv[v];
#pragma unroll
    for (int j = 0; j < 16; j++) {
        float acc = 0.f;
#pragma unroll
        for (int k = 0; k < 9; k++) acc += xi[k] * W1[k * 16 + j];
        hs[v * 16 + j] = acc * di;
    }
}

// ---- pull layer 1 (float4: 4 lanes/node) + fused layer-2 node transform ----
__global__ void k_pullA(const int* __restrict__ rowptr, const int* __restrict__ srcs,
                        const float4* __restrict__ hs4, const float* __restrict__ dinv,
                        const float4* __restrict__ b14, const float4* __restrict__ W24,
                        float4* __restrict__ hs24, int N) {
    int tid = blockIdx.x * 256 + threadIdx.x;
    int v = tid >> 2;
    int q = tid & 3;
    if (v >= N) return;
    int s = rowptr[v], e = rowptr[v + 1];
    float4 acc = hs4[v * 4 + q];   // self loop
    int k = s;
    for (; k + 4 <= e; k += 4) {
        int r0 = srcs[k], r1 = srcs[k + 1], r2 = srcs[k + 2], r3 = srcs[k + 3];
        float4 a0 = hs4[r0 * 4 + q];
        float4 a1 = hs4[r1 * 4 + q];
        float4 a2 = hs4[r2 * 4 + q];
        float4 a3 = hs4[r3 * 4 + q];
        acc.x += a0.x + a1.x + a2.x + a3.x;
        acc.y += a0.y + a1.y + a2.y + a3.y;
        acc.z += a0.z + a1.z + a2.z + a3.z;
        acc.w += a0.w + a1.w + a2.w + a3.w;
    }
    for (; k < e; k++) {
        float4 a = hs4[srcs[k] * 4 + q];
        acc.x += a.x; acc.y += a.y; acc.z += a.z; acc.w += a.w;
    }
    float di = dinv[v];
    float4 bb = b14[q];
    float h1[4];
    h1[0] = acc.x * di + bb.x; h1[0] = h1[0] > 0.f ? h1[0] : 0.f;
    h1[1] = acc.y * di + bb.y; h1[1] = h1[1] > 0.f ? h1[1] : 0.f;
    h1[2] = acc.z * di + bb.z; h1[2] = h1[2] > 0.f ? h1[2] : 0.f;
    h1[3] = acc.w * di + bb.w; h1[3] = h1[3] > 0.f ? h1[3] : 0.f;
    float4 o = make_float4(0.f, 0.f, 0.f, 0.f);
#pragma unroll
    for (int kk = 0; kk < 16; kk++) {
        float hk = __shfl(h1[kk & 3], kk >> 2, 4);
        float4 w = W24[kk * 4 + q];
        o.x += hk * w.x; o.y += hk * w.y; o.z += hk * w.z; o.w += hk * w.w;
    }
    o.x *= di; o.y *= di; o.z *= di; o.w *= di;
    hs24[v * 4 + q] = o;
}

// ---- pull layer 2 (float4): agg = hs2[v] + sum hs2[r] ----
__global__ void k_pullB(const int* __restrict__ rowptr, const int* __restrict__ srcs,
                        const float4* __restrict__ hs24, float4* __restrict__ agg4, int N) {
    int tid = blockIdx.x * 256 + threadIdx.x;
    int v = tid >> 2;
    int q = tid & 3;
    if (v >= N) return;
    int s = rowptr[v], e = rowptr[v + 1];
    float4 acc = hs24[v * 4 + q];
    int k = s;
    for (; k + 4 <= e; k += 4) {
        int r0 = srcs[k], r1 = srcs[k + 1], r2 = srcs[k + 2], r3 = srcs[k + 3];
        float4 a0 = hs24[r0 * 4 + q];
        float4 a1 = hs24[r1 * 4 + q];
        float4 a2 = hs24[r2 * 4 + q];
        float4 a3 = hs24[r3 * 4 + q];
        acc.x += a0.x + a1.x + a2.x + a3.x;
        acc.y += a0.y + a1.y + a2.y + a3.y;
        acc.z += a0.z + a1.z + a2.z + a3.z;
        acc.w += a0.w + a1.w + a2.w + a3.w;
    }
    for (; k < e; k++) {
        float4 a = hs24[srcs[k] * 4 + q];
        acc.x += a.x; acc.y += a.y; acc.z += a.z; acc.w += a.w;
    }
    agg4[v * 4 + q] = acc;
}

// ---- pool exploiting sorted batch ----
__global__ void k_pool2(const float* __restrict__ agg, const float* __restrict__ dinv,
                        const float* __restrict__ b2, const int* __restrict__ batch,
                        float* __restrict__ pooled, float* __restrict__ cnt, int n) {
    int tid = blockIdx.x * 256 + threadIdx.x;
    int chunk = tid >> 4;
    int j = tid & 15;
    int start = chunk * POOL_CH;
    if (start >= n) return;
    int end = start + POOL_CH;
    if (end > n) end = n;
    float bj = b2[j];
    int g_cur = batch[start];
    float acc = 0.f;
    float c_acc = 0.f;
    for (int v = start; v < end; v++) {
        int g = batch[v];
        if (g != g_cur) {
            atomicAdd(&pooled[g_cur * 16 + j], acc);
            if (j == 0) atomicAdd(&cnt[g_cur], c_acc);
            acc = 0.f; c_acc = 0.f; g_cur = g;
        }
        float t = agg[v * 16 + j] * dinv[v] + bj;
        acc += t > 0.f ? t : 0.f;
        c_acc += 1.f;
    }
    atomicAdd(&pooled[g_cur * 16 + j], acc);
    if (j == 0) atomicAdd(&cnt[g_cur], c_acc);
}

// ---- head MLP ----
__global__ void k_head(const float* __restrict__ pooled, const float* __restrict__ cnt,
                       const float* __restrict__ meta, const float* __restrict__ Wh1,
                       const float* __restrict__ bh1, const float* __restrict__ Wh2,
                       const float* __restrict__ bh2, float* __restrict__ out, int G) {
    int g = blockIdx.x * 256 + threadIdx.x;
    if (g >= G) return;
    float z[43];
    float c = cnt[g];
    c = c > 1.f ? c : 1.f;
#pragma unroll
    for (int j = 0; j < 16; j++) z[j] = pooled[g * 16 + j] / c;
#pragma unroll
    for (int j = 0; j < 27; j++) z[16 + j] = meta[g * 27 + j];
    float acc2 = bh2[0];
#pragma unroll
    for (int jj = 0; jj < 16; jj++) {
        float a = bh1[jj];
#pragma unroll
        for (int k = 0; k < 43; k++) a += z[k] * Wh1[k * 16 + jj];
        a = a > 0.f ? a : 0.f;
        acc2 += a * Wh2[jj];
    }
    out[g] = acc2;
}

extern "C" void kernel_launch(void* const* d_in, const int* in_sizes, int n_in,
                              void* d_out, int out_size, void* d_ws, size_t ws_size,
                              hipStream_t stream) {
    const float* x    = (const float*)d_in[0];
    const int*   ei   = (const int*)d_in[1];   // [2, E]: row then col
    const int*   batch= (const int*)d_in[2];
    const float* meta = (const float*)d_in[3];
    const float* W1   = (const float*)d_in[4];
    const float* b1   = (const float*)d_in[5];
    const float* W2   = (const float*)d_in[6];
    const float* b2   = (const float*)d_in[7];
    const float* Wh1  = (const float*)d_in[8];
    const float* bh1  = (const float*)d_in[9];
    const float* Wh2  = (const float*)d_in[10];
    const float* bh2  = (const float*)d_in[11];
    float* out = (float*)d_out;

    const int N = N_NODES, E = N_EDGES, G = N_GRAPHS;
    const int* row = ei;
    const int* col = ei + E;

    // workspace layout (4-byte units).
    // packed (9.01M words, fixed-capacity buckets) aliases hs+hs2 region:
    // dead after k_csr, before k_l1/pullA write hs/hs2.
    float*    ws      = (float*)d_ws;
    float*    dinv    = ws;                          // N (pad 512000)
    float*    hs      = ws + 512000;                 // N*16 (alias: packed head, agg)
    float*    hs2     = hs + 8000000;                // N*16 (alias: packed tail)
    int*      srcs    = (int*)(hs2 + 8000000);       // E
    float*    pooled  = (float*)(srcs + 8000000);    // G*16
    float*    cnt     = pooled + G * 16;             // G
    int*      gcursor = (int*)(cnt + G);             // NB (pad 512)
    int*      goff    = gcursor + 512;               // NB+1 (pad 512)
    int*      rowptr  = goff + 512;                  // N+1
    unsigned* packed  = (unsigned*)hs;               // NB*C_CAP = 9,013,248 (alias)
    float*    agg     = hs;                          // alias (hs dead after pullA)

    dim3 blk(256);
    int gN = (N + 255) / 256;

    // ---- one-pass bucket build + CSR ----
    k_fill<<<(G * 17 + 255) / 256, blk, 0, stream>>>(pooled, 0.0f, G * 17);
    k_initcur<<<(NB + 255) / 256, blk, 0, stream>>>(gcursor);
    k_build<<<NTB2, blk, 0, stream>>>((const int4*)row, (const int4*)col,
                                      gcursor, packed, E);
    k_cnt2off<<<1, blk, 0, stream>>>(gcursor, goff);
    k_csr<<<NB, blk, 0, stream>>>(packed, goff, srcs, rowptr, dinv, N);

    // ---- layer 1 (+fused layer-2 transform) ----
    k_l1<<<gN, blk, 0, stream>>>(x, W1, dinv, hs, N);
    int gP4 = (N * 4 + 255) / 256;
    k_pullA<<<gP4, blk, 0, stream>>>(rowptr, srcs, (const float4*)hs, dinv,
                                     (const float4*)b1, (const float4*)W2,
                                     (float4*)hs2, N);

    // ---- layer 2 aggregation ----
    k_pullB<<<gP4, blk, 0, stream>>>(rowptr, srcs, (const float4*)hs2, (float4*)agg, N);

    // ---- pool + head ----
    int chunks = (N + POOL_CH - 1) / POOL_CH;
    int gPool = (chunks * 16 + 255) / 256;
    k_pool2<<<gPool, blk, 0, stream>>>(agg, dinv, b2, batch, pooled, cnt, N);
    k_head<<<(G + 255) / 256, blk, 0, stream>>>(pooled, cnt, meta, Wh1, bh1, Wh2, bh2, out, G);
}

// Round 9
// 627.359 us; speedup vs baseline: 2.8433x; 1.0465x over previous
//
#include <hip/hip_runtime.h>

#define N_NODES 500000
#define N_EDGES 8000000
#define N_GRAPHS 8192
#define POOL_CH 128
#define BKT 1024                // nodes per bucket
#define NB 489                  // ceil(N_NODES / BKT)
#define C_CAP 17408             // bucket capacity: mean 16361 + ~8 sigma
#define TILE2 8192              // edges per build block
#define NTB2 977                // ceil(N_EDGES / TILE2)

// ---- bf16x2 <-> fp32 helpers (RNE) ----
__device__ __forceinline__ void bf2x(unsigned u, float& lo, float& hi) {
    union { unsigned i; float f; } a, b;
    a.i = u << 16; b.i = u & 0xFFFF0000u;
    lo = a.f; hi = b.f;
}
__device__ __forceinline__ unsigned f2bf2(float lo, float hi) {
    union { float f; unsigned i; } a, b;
    a.f = lo; b.f = hi;
    unsigned rl = (a.i + 0x7FFFu + ((a.i >> 16) & 1u)) >> 16;
    unsigned rh = (b.i + 0x7FFFu + ((b.i >> 16) & 1u)) & 0xFFFF0000u;
    return rl | rh;
}
__device__ __forceinline__ void addbf(float* acc, uint4 a) {
    float lo, hi;
    bf2x(a.x, lo, hi); acc[0] += lo; acc[1] += hi;
    bf2x(a.y, lo, hi); acc[2] += lo; acc[3] += hi;
    bf2x(a.z, lo, hi); acc[4] += lo; acc[5] += hi;
    bf2x(a.w, lo, hi); acc[6] += lo; acc[7] += hi;
}

// ---------------- utility ----------------
__global__ void k_fill(float* __restrict__ p, float v, int n) {
    int i = blockIdx.x * 256 + threadIdx.x;
    if (i < n) p[i] = v;
}

__global__ void k_initcur(int* __restrict__ gcursor) {
    int i = blockIdx.x * 256 + threadIdx.x;
    if (i < NB) gcursor[i] = i * C_CAP;
}

// ---- one-pass bucket build: read edges once, stage in LDS, claim runs ----
__global__ void k_build(const int4* __restrict__ row4, const int4* __restrict__ col4,
                        int* __restrict__ gcursor, unsigned* __restrict__ packed, int E) {
    __shared__ unsigned stage[TILE2];          // 32 KB: (r<<10)|(c&1023)
    __shared__ unsigned short bkt[TILE2];      // 16 KB
    __shared__ int hist[NB];
    __shared__ int runbase[NB];
    int t = threadIdx.x, b = blockIdx.x;
    for (int i = t; i < NB; i += 256) hist[i] = 0;
    __syncthreads();
#pragma unroll
    for (int k = 0; k < 8; k++) {
        int li4 = k * 256 + t;
        int vi = b * 2048 + li4;
        int idx = li4 * 4;
        if (vi * 4 < E) {                      // E % 4 == 0: whole int4 valid
            int4 c = col4[vi];
            int4 r = row4[vi];
            unsigned cc, rr;
            cc = (unsigned)c.x; rr = (unsigned)r.x;
            if (cc < N_NODES && rr < N_NODES) { stage[idx] = (rr << 10) | (cc & 1023u); bkt[idx] = (unsigned short)(cc >> 10); atomicAdd(&hist[cc >> 10], 1); } else bkt[idx] = 0xFFFFu;
            cc = (unsigned)c.y; rr = (unsigned)r.y;
            if (cc < N_NODES && rr < N_NODES) { stage[idx+1] = (rr << 10) | (cc & 1023u); bkt[idx+1] = (unsigned short)(cc >> 10); atomicAdd(&hist[cc >> 10], 1); } else bkt[idx+1] = 0xFFFFu;
            cc = (unsigned)c.z; rr = (unsigned)r.z;
            if (cc < N_NODES && rr < N_NODES) { stage[idx+2] = (rr << 10) | (cc & 1023u); bkt[idx+2] = (unsigned short)(cc >> 10); atomicAdd(&hist[cc >> 10], 1); } else bkt[idx+2] = 0xFFFFu;
            cc = (unsigned)c.w; rr = (unsigned)r.w;
            if (cc < N_NODES && rr < N_NODES) { stage[idx+3] = (rr << 10) | (cc & 1023u); bkt[idx+3] = (unsigned short)(cc >> 10); atomicAdd(&hist[cc >> 10], 1); } else bkt[idx+3] = 0xFFFFu;
        } else {
            bkt[idx] = 0xFFFFu; bkt[idx+1] = 0xFFFFu; bkt[idx+2] = 0xFFFFu; bkt[idx+3] = 0xFFFFu;
        }
    }
    __syncthreads();
    for (int i = t; i < NB; i += 256) {
        int c = hist[i];
        runbase[i] = c ? atomicAdd(&gcursor[i], c) : 0;
        hist[i] = 0;
    }
    __syncthreads();
    for (int i = t; i < TILE2; i += 256) {
        unsigned bb = bkt[i];
        if (bb != 0xFFFFu) {
            int pos = runbase[bb] + atomicAdd(&hist[bb], 1);
            packed[pos] = stage[i];
        }
    }
}

// ---- end-cursors -> compact exclusive offsets goff[NB+1] (single block) ----
__global__ void k_cnt2off(const int* __restrict__ gcursor, int* __restrict__ goff) {
    __shared__ int sd[256];
    int t = threadIdx.x;
    int v[2]; int s = 0;
#pragma unroll
    for (int k = 0; k < 2; k++) {
        int i = t * 2 + k;
        v[k] = (i < NB) ? (gcursor[i] - i * C_CAP) : 0;
        s += v[k];
    }
    sd[t] = s; __syncthreads();
    for (int d = 1; d < 256; d <<= 1) {
        int tv = (t >= d) ? sd[t - d] : 0;
        __syncthreads(); sd[t] += tv; __syncthreads();
    }
    int run = sd[t] - s;
#pragma unroll
    for (int k = 0; k < 2; k++) {
        int i = t * 2 + k;
        if (i < NB) goff[i] = run;
        run += v[k];
    }
    if (t == 255) goff[NB] = sd[255];
}

// ---- per-bucket packed -> compact CSR + rowptr + dinv ----
__global__ void k_csr(const unsigned* __restrict__ packed, const int* __restrict__ goff,
                      int* __restrict__ srcs, int* __restrict__ rowptr,
                      float* __restrict__ dinv, int N) {
    __shared__ int hist[BKT];
    __shared__ int off[BKT];
    __shared__ int sd[256];
    int t = threadIdx.x, b = blockIdx.x;
    int gbase = goff[b];
    int cnt = goff[b + 1] - gbase;
    int sfix = b * C_CAP;
    for (int k = t; k < BKT; k += 256) hist[k] = 0;
    __syncthreads();
    for (int i = t; i < cnt; i += 256)
        atomicAdd(&hist[packed[sfix + i] & 1023u], 1);
    __syncthreads();
    int ls[4]; int s = 0;
#pragma unroll
    for (int k = 0; k < 4; k++) { ls[k] = hist[t * 4 + k]; s += ls[k]; }
    sd[t] = s; __syncthreads();
    for (int d = 1; d < 256; d <<= 1) {
        int tv = (t >= d) ? sd[t - d] : 0;
        __syncthreads(); sd[t] += tv; __syncthreads();
    }
    int run = sd[t] - s;
#pragma unroll
    for (int k = 0; k < 4; k++) {
        off[t * 4 + k] = run;
        int v = b * BKT + t * 4 + k;
        if (v < N) {
            rowptr[v] = gbase + run;
            dinv[v] = rsqrtf(1.0f + (float)ls[k]);
        }
        run += ls[k];
    }
    if (b == NB - 1 && t == 255) rowptr[N] = gbase + run;
    __syncthreads();
    for (int k = t; k < BKT; k += 256) hist[k] = 0;
    __syncthreads();
    for (int i = t; i < cnt; i += 256) {
        unsigned w = packed[sfix + i];
        unsigned c = w & 1023u;
        int p = off[c] + atomicAdd(&hist[c], 1);
        srcs[gbase + p] = (int)(w >> 10);
    }
}

// ---- layer-1 node transform: hs(bf16) = (x @ W1) * dinv ----
__global__ void k_l1(const float* __restrict__ x, const float* __restrict__ W1,
                     const float* __restrict__ dinv, uint4* __restrict__ hsu, int n) {
    int v = blockIdx.x * 256 + threadIdx.x;
    if (v >= n) return;
    float xi[9];
#pragma unroll
    for (int k = 0; k < 9; k++) xi[k] = x[v * 9 + k];
    float di = dinv[v];
    float h[16];
#pragma unroll
    for (int j = 0; j < 16; j++) {
        float acc = 0.f;
#pragma unroll
        for (int k = 0; k < 9; k++) acc += xi[k] * W1[k * 16 + j];
        h[j] = acc * di;
    }
    uint4 w0, w1;
    w0.x = f2bf2(h[0], h[1]);  w0.y = f2bf2(h[2], h[3]);
    w0.z = f2bf2(h[4], h[5]);  w0.w = f2bf2(h[6], h[7]);
    w1.x = f2bf2(h[8], h[9]);  w1.y = f2bf2(h[10], h[11]);
    w1.z = f2bf2(h[12], h[13]); w1.w = f2bf2(h[14], h[15]);
    hsu[v * 2] = w0;
    hsu[v * 2 + 1] = w1;
}

// ---- pull layer 1 (bf16, 2 lanes/node) + fused layer-2 node transform ----
__global__ void k_pullA(const int* __restrict__ rowptr, const int* __restrict__ srcs,
                        const uint4* __restrict__ hsu, const float* __restrict__ dinv,
                        const float* __restrict__ b1, const float* __restrict__ W2,
                        uint4* __restrict__ hs2u, int N) {
    int tid = blockIdx.x * 256 + threadIdx.x;
    int v = tid >> 1;
    int q = tid & 1;             // which 8-feature half
    if (v >= N) return;
    int s = rowptr[v], e = rowptr[v + 1];
    float acc[8];
    {
        uint4 u = hsu[v * 2 + q];   // self loop
        bf2x(u.x, acc[0], acc[1]); bf2x(u.y, acc[2], acc[3]);
        bf2x(u.z, acc[4], acc[5]); bf2x(u.w, acc[6], acc[7]);
    }
    int k = s;
    for (; k + 4 <= e; k += 4) {
        int r0 = srcs[k], r1 = srcs[k + 1], r2 = srcs[k + 2], r3 = srcs[k + 3];
        uint4 a0 = hsu[r0 * 2 + q];
        uint4 a1 = hsu[r1 * 2 + q];
        uint4 a2 = hsu[r2 * 2 + q];
        uint4 a3 = hsu[r3 * 2 + q];
        addbf(acc, a0); addbf(acc, a1); addbf(acc, a2); addbf(acc, a3);
    }
    for (; k < e; k++) addbf(acc, hsu[srcs[k] * 2 + q]);
    float di = dinv[v];
    float h1[8];
#pragma unroll
    for (int i = 0; i < 8; i++) {
        float tt = acc[i] * di + b1[q * 8 + i];
        h1[i] = tt > 0.f ? tt : 0.f;
    }
    float o[8] = {0.f, 0.f, 0.f, 0.f, 0.f, 0.f, 0.f, 0.f};
#pragma unroll
    for (int kk = 0; kk < 16; kk++) {
        float hk = __shfl(h1[kk & 7], kk >> 3, 2);
#pragma unroll
        for (int i = 0; i < 8; i++) o[i] += hk * W2[kk * 16 + q * 8 + i];
    }
#pragma unroll
    for (int i = 0; i < 8; i++) o[i] *= di;
    uint4 w;
    w.x = f2bf2(o[0], o[1]); w.y = f2bf2(o[2], o[3]);
    w.z = f2bf2(o[4], o[5]); w.w = f2bf2(o[6], o[7]);
    hs2u[v * 2 + q] = w;
}

// ---- pull layer 2 (bf16 in, fp32 agg out) ----
__global__ void k_pullB(const int* __restrict__ rowptr, const int* __restrict__ srcs,
                        const uint4* __restrict__ hs2u, float4* __restrict__ agg4, int N) {
    int tid = blockIdx.x * 256 + threadIdx.x;
    int v = tid >> 1;
    int q = tid & 1;
    if (v >= N) return;
    int s = rowptr[v], e = rowptr[v + 1];
    float acc[8];
    {
        uint4 u = hs2u[v * 2 + q];
        bf2x(u.x, acc[0], acc[1]); bf2x(u.y, acc[2], acc[3]);
        bf2x(u.z, acc[4], acc[5]); bf2x(u.w, acc[6], acc[7]);
    }
    int k = s;
    for (; k + 4 <= e; k += 4) {
        int r0 = srcs[k], r1 = srcs[k + 1], r2 = srcs[k + 2], r3 = srcs[k + 3];
        uint4 a0 = hs2u[r0 * 2 + q];
        uint4 a1 = hs2u[r1 * 2 + q];
        uint4 a2 = hs2u[r2 * 2 + q];
        uint4 a3 = hs2u[r3 * 2 + q];
        addbf(acc, a0); addbf(acc, a1); addbf(acc, a2); addbf(acc, a3);
    }
    for (; k < e; k++) addbf(acc, hs2u[srcs[k] * 2 + q]);
    float4 o0, o1;
    o0.x = acc[0]; o0.y = acc[1]; o0.z = acc[2]; o0.w = acc[3];
    o1.x = acc[4]; o1.y = acc[5]; o1.z = acc[6]; o1.w = acc[7];
    agg4[v * 4 + q * 2] = o0;
    agg4[v * 4 + q * 2 + 1] = o1;
}

// ---- pool exploiting sorted batch ----
__global__ void k_pool2(const float* __restrict__ agg, const float* __restrict__ dinv,
                        const float* __restrict__ b2, const int* __restrict__ batch,
                        float* __restrict__ pooled, float* __restrict__ cnt, int n) {
    int tid = blockIdx.x * 256 + threadIdx.x;
    int chunk = tid >> 4;
    int j = tid & 15;
    int start = chunk * POOL_CH;
    if (start >= n) return;
    int end = start + POOL_CH;
    if (end > n) end = n;
    float bj = b2[j];
    int g_cur = batch[start];
    float acc = 0.f;
    float c_acc = 0.f;
    for (int v = start; v < end; v++) {
        int g = batch[v];
        if (g != g_cur) {
            atomicAdd(&pooled[g_cur * 16 + j], acc);
            if (j == 0) atomicAdd(&cnt[g_cur], c_acc);
            acc = 0.f; c_acc = 0.f; g_cur = g;
        }
        float t = agg[v * 16 + j] * dinv[v] + bj;
        acc += t > 0.f ? t : 0.f;
        c_acc += 1.f;
    }
    atomicAdd(&pooled[g_cur * 16 + j], acc);
    if (j == 0) atomicAdd(&cnt[g_cur], c_acc);
}

// ---- head MLP ----
__global__ void k_head(const float* __restrict__ pooled, const float* __restrict__ cnt,
                       const float* __restrict__ meta, const float* __restrict__ Wh1,
                       const float* __restrict__ bh1, const float* __restrict__ Wh2,
                       const float* __restrict__ bh2, float* __restrict__ out, int G) {
    int g = blockIdx.x * 256 + threadIdx.x;
    if (g >= G) return;
    float z[43];
    float c = cnt[g];
    c = c > 1.f ? c : 1.f;
#pragma unroll
    for (int j = 0; j < 16; j++) z[j] = pooled[g * 16 + j] / c;
#pragma unroll
    for (int j = 0; j < 27; j++) z[16 + j] = meta[g * 27 + j];
    float acc2 = bh2[0];
#pragma unroll
    for (int jj = 0; jj < 16; jj++) {
        float a = bh1[jj];
#pragma unroll
        for (int k = 0; k < 43; k++) a += z[k] * Wh1[k * 16 + jj];
        a = a > 0.f ? a : 0.f;
        acc2 += a * Wh2[jj];
    }
    out[g] = acc2;
}

extern "C" void kernel_launch(void* const* d_in, const int* in_sizes, int n_in,
                              void* d_out, int out_size, void* d_ws, size_t ws_size,
                              hipStream_t stream) {
    const float* x    = (const float*)d_in[0];
    const int*   ei   = (const int*)d_in[1];   // [2, E]: row then col
    const int*   batch= (const int*)d_in[2];
    const float* meta = (const float*)d_in[3];
    const float* W1   = (const float*)d_in[4];
    const float* b1   = (const float*)d_in[5];
    const float* W2   = (const float*)d_in[6];
    const float* b2   = (const float*)d_in[7];
    const float* Wh1  = (const float*)d_in[8];
    const float* bh1  = (const float*)d_in[9];
    const float* Wh2  = (const float*)d_in[10];
    const float* bh2  = (const float*)d_in[11];
    float* out = (float*)d_out;

    const int N = N_NODES, E = N_EDGES, G = N_GRAPHS;
    const int* row = ei;
    const int* col = ei + E;

    // workspace layout (4-byte units), total ~102.7 MB (<= 104.5 MB used in R5):
    //   packed (NB*C_CAP = 8,512,512 w) lives in its own region; dead after
    //   k_csr, reused as fp32 agg (8,000,000 w) from k_pullB on.
    //   hs/hs2 are bf16 (16 B/node = 2 uint4/node), 4,000,000 w each.
    float*    ws      = (float*)d_ws;
    float*    dinv    = ws;                          // 512,000
    unsigned* packed  = (unsigned*)(ws + 512000);    // 8,512,512 (alias: agg)
    unsigned* hsu     = packed + 8512512;            // 4,000,000 (bf16 hs)
    unsigned* hs2u    = hsu + 4000000;               // 4,000,000 (bf16 hs2)
    int*      srcs    = (int*)(hs2u + 4000000);      // 8,000,000
    float*    pooled  = (float*)(srcs + 8000000);    // 131,072
    float*    cnt     = pooled + G * 16;             // 8,192
    int*      gcursor = (int*)(cnt + G);             // 512
    int*      goff    = gcursor + 512;               // 512
    int*      rowptr  = goff + 512;                  // 500,001
    float*    agg     = (float*)packed;              // alias

    dim3 blk(256);
    int gN = (N + 255) / 256;

    // ---- one-pass bucket build + CSR ----
    k_fill<<<(G * 17 + 255) / 256, blk, 0, stream>>>(pooled, 0.0f, G * 17);
    k_initcur<<<(NB + 255) / 256, blk, 0, stream>>>(gcursor);
    k_build<<<NTB2, blk, 0, stream>>>((const int4*)row, (const int4*)col,
                                      gcursor, packed, E);
    k_cnt2off<<<1, blk, 0, stream>>>(gcursor, goff);
    k_csr<<<NB, blk, 0, stream>>>(packed, goff, srcs, rowptr, dinv, N);

    // ---- layer 1 (+fused layer-2 transform) ----
    k_l1<<<gN, blk, 0, stream>>>(x, W1, dinv, (uint4*)hsu, N);
    int gP2 = (N * 2 + 255) / 256;
    k_pullA<<<gP2, blk, 0, stream>>>(rowptr, srcs, (const uint4*)hsu, dinv,
                                     b1, W2, (uint4*)hs2u, N);

    // ---- layer 2 aggregation ----
    k_pullB<<<gP2, blk, 0, stream>>>(rowptr, srcs, (const uint4*)hs2u,
                                     (float4*)agg, N);

    // ---- pool + head ----
    int chunks = (N + POOL_CH - 1) / POOL_CH;
    int gPool = (chunks * 16 + 255) / 256;
    k_pool2<<<gPool, blk, 0, stream>>>(agg, dinv, b2, batch, pooled, cnt, N);
    k_head<<<(G + 255) / 256, blk, 0, stream>>>(pooled, cnt, meta, Wh1, bh1, Wh2, bh2, out, G);
}